// Round 4
// baseline (563.837 us; speedup 1.0000x reference)
//
#include <hip/hip_runtime.h>

#define BB 8
#define NN 16384
#define DIMD 512
#define MVV 8
#define SCALE_C 0.1f
#define EPS_C 1e-5f

typedef unsigned int u32;
typedef float f32x4 __attribute__((ext_vector_type(4)));

// load 8 contiguous fp32 (16B aligned) -> 8 fp32
__device__ __forceinline__ void load8f(const float* __restrict__ p, float* f) {
    float4 a = *(const float4*)p;
    float4 b = *(const float4*)(p + 4);
    f[0] = a.x; f[1] = a.y; f[2] = a.z; f[3] = a.w;
    f[4] = b.x; f[5] = b.y; f[6] = b.z; f[7] = b.w;
}

__global__ __launch_bounds__(256) void kzero(float* __restrict__ p, int n) {
    int i = blockIdx.x * 256 + threadIdx.x;
    if (i < n) p[i] = 0.0f;
}

// ---------------------------------------------------------------------------
// BIG-WORKSPACE PATH
// Pass 1: column sums of x over N  AND  per-token pm[i] = dot(x_row, Wp[i,:]).
// pm shuffles live here (BW-bound kernel, idle VALU). grid (128,8), block 256.
__global__ __launch_bounds__(256) void kmean2(const float* __restrict__ x,
                                              const float* __restrict__ Wp,
                                              float* __restrict__ wsum,
                                              float* __restrict__ pmws) {
    const int b = blockIdx.y;
    const int chunk = blockIdx.x;           // 0..127
    const int t = threadIdx.x;
    const int l = t & 63;
    const int rt = t >> 6;                  // wave id 0..3
    const int d0 = l * 8;
    const bool b5 = (l & 32) != 0;
    const bool b4 = (l & 16) != 0;
    const bool b3 = (l & 8) != 0;
    const long rowbase = (long)b * NN + (long)chunk * 128;
    const long base = rowbase * DIMD;

    float wp[8][8];
#pragma unroll
    for (int i = 0; i < 8; i++) load8f(Wp + i * DIMD + d0, wp[i]);

    float acc[8];
#pragma unroll
    for (int j = 0; j < 8; j++) acc[j] = 0.0f;

    for (int r = rt; r < 128; r += 16) {
        const float* p0 = x + base + (long)r * DIMD + d0;
        float f[4][8];
        load8f(p0, f[0]);
        load8f(p0 + 4L * DIMD, f[1]);
        load8f(p0 + 8L * DIMD, f[2]);
        load8f(p0 + 12L * DIMD, f[3]);
#pragma unroll
        for (int j = 0; j < 8; j++) acc[j] += (f[0][j] + f[1][j]) + (f[2][j] + f[3][j]);

        // pm partials for 4 rows, interleaved
        float pmp[4][8];
#pragma unroll
        for (int u = 0; u < 4; u++)
#pragma unroll
            for (int i = 0; i < 8; i++) {
                float p = f[u][0] * wp[i][0];
#pragma unroll
                for (int j = 1; j < 8; j++) p += f[u][j] * wp[i][j];
                pmp[u][i] = p;
            }

        // reduce-scatter: lane bits 5,4,3 pick value bits 2,1,0
        float k1[4][4];
#pragma unroll
        for (int u = 0; u < 4; u++)
#pragma unroll
            for (int j = 0; j < 4; j++) {
                float send = b5 ? pmp[u][j] : pmp[u][j + 4];
                float recv = __shfl_xor(send, 32, 64);
                k1[u][j] = (b5 ? pmp[u][j + 4] : pmp[u][j]) + recv;
            }
        float k2[4][2];
#pragma unroll
        for (int u = 0; u < 4; u++)
#pragma unroll
            for (int j = 0; j < 2; j++) {
                float send = b4 ? k1[u][j] : k1[u][j + 2];
                float recv = __shfl_xor(send, 16, 64);
                k2[u][j] = (b4 ? k1[u][j + 2] : k1[u][j]) + recv;
            }
        float tv[4];
#pragma unroll
        for (int u = 0; u < 4; u++) {
            float ts = b3 ? k2[u][0] : k2[u][1];
            float tr = __shfl_xor(ts, 8, 64);
            tv[u] = (b3 ? k2[u][1] : k2[u][0]) + tr;
        }
        // allreduce over lane bits 2..0
#pragma unroll
        for (int u = 0; u < 4; u++) tv[u] += __shfl_xor(tv[u], 4, 64);
#pragma unroll
        for (int u = 0; u < 4; u++) tv[u] += __shfl_xor(tv[u], 2, 64);
#pragma unroll
        for (int u = 0; u < 4; u++) tv[u] += __shfl_xor(tv[u], 1, 64);
        // pack pm[0..7] to lanes 0..7 and store 32B per token
#pragma unroll
        for (int u = 0; u < 4; u++) {
            float pv = __shfl(tv[u], (l & 7) << 3, 64);
            if (l < 8) pmws[(rowbase + r + 4 * u) * 8 + l] = pv;
        }
    }

    __shared__ float red[256][9];
#pragma unroll
    for (int j = 0; j < 8; j++) red[t][j] = acc[j];
    __syncthreads();

    if (t < 64) {
        float s[8];
#pragma unroll
        for (int j = 0; j < 8; j++)
            s[j] = red[t][j] + red[t + 64][j] + red[t + 128][j] + red[t + 192][j];
        float* dst = wsum + b * DIMD + t * 8;
#pragma unroll
        for (int j = 0; j < 8; j++) atomicAdd(dst + j, s[j]);
    }
}

// Pass 3 (big-ws): no Wp dot, no pm shuffle chain — pm read as uniform 32B.
// grid (128,8), block 256, 2 rows/wave phase-interleaved, reverse traversal.
__global__ __launch_bounds__(256, 2) void kmain2(const float* __restrict__ x,
                                                 const float* __restrict__ gamma,
                                                 const float* __restrict__ beta,
                                                 const float* __restrict__ wot,
                                                 const float* __restrict__ c2,
                                                 const float* __restrict__ pmws,
                                                 float* __restrict__ out) {
    const int b = blockIdx.y;
    const int chunk = blockIdx.x;
    const int w = threadIdx.x >> 6;
    const int l = threadIdx.x & 63;
    const int d0 = l * 8;
    const bool b5 = (l & 32) != 0;

    float wo[8][8];
    const float* wotp = wot + ((long)b * DIMD + d0) * 8;
#pragma unroll
    for (int j = 0; j < 8; j++)
#pragma unroll
        for (int i = 0; i < 8; i++) wo[j][i] = wotp[j * 8 + i];

    float cc[8];
#pragma unroll
    for (int j = 0; j < 8; j++) cc[j] = c2[b * DIMD + d0 + j];

    float g[8], be[8];
    load8f(gamma + d0, g);
    load8f(beta + d0, be);

    const long rowbase = (long)b * NN + (long)chunk * 128;

    float xv[2][8], pmt[2][8];
    {
        const int r = 2 * w + 8 * 15;
        load8f(x + (rowbase + r) * DIMD + d0, xv[0]);
        load8f(x + (rowbase + r + 1) * DIMD + d0, xv[1]);
        load8f(pmws + (rowbase + r) * 8, pmt[0]);
        load8f(pmws + (rowbase + r + 1) * 8, pmt[1]);
    }

    for (int k = 15; k >= 0; k--) {
        const int r = 2 * w + 8 * k;

        float xn[2][8], pmn[2][8];
        if (k > 0) {
            load8f(x + (rowbase + r - 8) * DIMD + d0, xn[0]);
            load8f(x + (rowbase + r - 7) * DIMD + d0, xn[1]);
            load8f(pmws + (rowbase + r - 8) * 8, pmn[0]);
            load8f(pmws + (rowbase + r - 7) * 8, pmn[1]);
        }

        float yv[2][8], s1[2], s2[2];
#pragma unroll
        for (int u = 0; u < 2; u++) {
            s1[u] = 0.0f; s2[u] = 0.0f;
#pragma unroll
            for (int j = 0; j < 8; j++) {
                float o = cc[j];
#pragma unroll
                for (int i = 0; i < 8; i++) o += pmt[u][i] * wo[j][i];
                float y = xv[u][j] + SCALE_C * o;
                yv[u][j] = y;
                s1[u] += y;
                s2[u] += y * y;
            }
        }

        // paired LN reduction, rows interleaved
        float v[2];
#pragma unroll
        for (int u = 0; u < 2; u++) {
            float ls = b5 ? s1[u] : s2[u];
            v[u] = (b5 ? s2[u] : s1[u]) + __shfl_xor(ls, 32, 64);
        }
#pragma unroll
        for (int u = 0; u < 2; u++) v[u] += __shfl_xor(v[u], 16, 64);
#pragma unroll
        for (int u = 0; u < 2; u++) v[u] += __shfl_xor(v[u], 8, 64);
#pragma unroll
        for (int u = 0; u < 2; u++) v[u] += __shfl_xor(v[u], 4, 64);
#pragma unroll
        for (int u = 0; u < 2; u++) v[u] += __shfl_xor(v[u], 2, 64);
#pragma unroll
        for (int u = 0; u < 2; u++) v[u] += __shfl_xor(v[u], 1, 64);

#pragma unroll
        for (int u = 0; u < 2; u++) {
            float vw = __shfl_xor(v[u], 32, 64);
            float S1 = b5 ? vw : v[u];
            float S2 = b5 ? v[u] : vw;
            float mu = S1 * (1.0f / DIMD);
            float var = S2 * (1.0f / DIMD) - mu * mu;
            float rs = rsqrtf(var + EPS_C);

            float* po = out + (rowbase + r + u) * DIMD + d0;
            f32x4 o1 = { g[0] * (yv[u][0] - mu) * rs + be[0],
                         g[1] * (yv[u][1] - mu) * rs + be[1],
                         g[2] * (yv[u][2] - mu) * rs + be[2],
                         g[3] * (yv[u][3] - mu) * rs + be[3] };
            f32x4 o2 = { g[4] * (yv[u][4] - mu) * rs + be[4],
                         g[5] * (yv[u][5] - mu) * rs + be[5],
                         g[6] * (yv[u][6] - mu) * rs + be[6],
                         g[7] * (yv[u][7] - mu) * rs + be[7] };
            __builtin_nontemporal_store(o1, (f32x4*)po);
            __builtin_nontemporal_store(o2, (f32x4*)(po + 4));
        }

#pragma unroll
        for (int u = 0; u < 2; u++)
#pragma unroll
            for (int j = 0; j < 8; j++) { xv[u][j] = xn[u][j]; pmt[u][j] = pmn[u][j]; }
    }
}

// ---------------------------------------------------------------------------
// FALLBACK PATH (round-3 kernels, used when workspace < 4.2 MiB)
__global__ __launch_bounds__(256) void kmean(const float* __restrict__ x, float* __restrict__ wsum) {
    const int b = blockIdx.y;
    const int chunk = blockIdx.x;
    const int t = threadIdx.x;
    const int c = t & 63;
    const int rt = t >> 6;
    const long base = ((long)b * NN + (long)chunk * 128) * DIMD;

    float acc[8];
#pragma unroll
    for (int j = 0; j < 8; j++) acc[j] = 0.0f;

    for (int r = rt; r < 128; r += 16) {
        const float* p0 = x + base + (long)r * DIMD + c * 8;
        float f0[8], f1[8], f2[8], f3[8];
        load8f(p0, f0);
        load8f(p0 + 4L * DIMD, f1);
        load8f(p0 + 8L * DIMD, f2);
        load8f(p0 + 12L * DIMD, f3);
#pragma unroll
        for (int j = 0; j < 8; j++) acc[j] += (f0[j] + f1[j]) + (f2[j] + f3[j]);
    }

    __shared__ float red[256][9];
#pragma unroll
    for (int j = 0; j < 8; j++) red[t][j] = acc[j];
    __syncthreads();

    if (t < 64) {
        float s[8];
#pragma unroll
        for (int j = 0; j < 8; j++)
            s[j] = red[t][j] + red[t + 64][j] + red[t + 128][j] + red[t + 192][j];
        float* dst = wsum + b * DIMD + t * 8;
#pragma unroll
        for (int j = 0; j < 8; j++) atomicAdd(dst + j, s[j]);
    }
}

__global__ __launch_bounds__(256, 2) void kmain(const float* __restrict__ x,
                                                const float* __restrict__ Wp,
                                                const float* __restrict__ gamma,
                                                const float* __restrict__ beta,
                                                const float* __restrict__ wot,
                                                const float* __restrict__ c2,
                                                float* __restrict__ out) {
    const int b = blockIdx.y;
    const int chunk = blockIdx.x;
    const int w = threadIdx.x >> 6;
    const int l = threadIdx.x & 63;
    const int d0 = l * 8;
    const bool b5 = (l & 32) != 0;
    const bool b4 = (l & 16) != 0;
    const bool b3 = (l & 8) != 0;

    float wp[8][8];
#pragma unroll
    for (int i = 0; i < 8; i++) load8f(Wp + i * DIMD + d0, wp[i]);

    float wo[8][8];
    const float* wotp = wot + ((long)b * DIMD + d0) * 8;
#pragma unroll
    for (int j = 0; j < 8; j++)
#pragma unroll
        for (int i = 0; i < 8; i++) wo[j][i] = wotp[j * 8 + i];

    float cc[8];
#pragma unroll
    for (int j = 0; j < 8; j++) cc[j] = c2[b * DIMD + d0 + j];

    float g[8], be[8];
    load8f(gamma + d0, g);
    load8f(beta + d0, be);

    const long rowbase = (long)b * NN + (long)chunk * 128;

    float xv[2][8];
    {
        const int r = 2 * w + 8 * 15;
        load8f(x + (rowbase + r) * DIMD + d0, xv[0]);
        load8f(x + (rowbase + r + 1) * DIMD + d0, xv[1]);
    }

    for (int k = 15; k >= 0; k--) {
        const int r = 2 * w + 8 * k;

        float xn[2][8];
        if (k > 0) {
            load8f(x + (rowbase + r - 8) * DIMD + d0, xn[0]);
            load8f(x + (rowbase + r - 7) * DIMD + d0, xn[1]);
        }

        float pm[2][8];
#pragma unroll
        for (int u = 0; u < 2; u++)
#pragma unroll
            for (int i = 0; i < 8; i++) {
                float p = xv[u][0] * wp[i][0];
#pragma unroll
                for (int j = 1; j < 8; j++) p += xv[u][j] * wp[i][j];
                pm[u][i] = p;
            }

        float k1[2][4];
#pragma unroll
        for (int u = 0; u < 2; u++)
#pragma unroll
            for (int j = 0; j < 4; j++) {
                float send = b5 ? pm[u][j] : pm[u][j + 4];
                float recv = __shfl_xor(send, 32, 64);
                k1[u][j] = (b5 ? pm[u][j + 4] : pm[u][j]) + recv;
            }
        float k2[2][2];
#pragma unroll
        for (int u = 0; u < 2; u++)
#pragma unroll
            for (int j = 0; j < 2; j++) {
                float send = b4 ? k1[u][j] : k1[u][j + 2];
                float recv = __shfl_xor(send, 16, 64);
                k2[u][j] = (b4 ? k1[u][j + 2] : k1[u][j]) + recv;
            }
        float t[2];
#pragma unroll
        for (int u = 0; u < 2; u++) {
            float ts = b3 ? k2[u][0] : k2[u][1];
            float tr = __shfl_xor(ts, 8, 64);
            t[u] = (b3 ? k2[u][1] : k2[u][0]) + tr;
        }
#pragma unroll
        for (int u = 0; u < 2; u++) t[u] += __shfl_xor(t[u], 4, 64);
#pragma unroll
        for (int u = 0; u < 2; u++) t[u] += __shfl_xor(t[u], 2, 64);
#pragma unroll
        for (int u = 0; u < 2; u++) t[u] += __shfl_xor(t[u], 1, 64);
        float pmt[2][8];
#pragma unroll
        for (int u = 0; u < 2; u++)
#pragma unroll
            for (int i = 0; i < 8; i++) pmt[u][i] = __shfl(t[u], i << 3, 64);

        float yv[2][8], s1[2], s2[2];
#pragma unroll
        for (int u = 0; u < 2; u++) {
            s1[u] = 0.0f; s2[u] = 0.0f;
#pragma unroll
            for (int j = 0; j < 8; j++) {
                float o = cc[j];
#pragma unroll
                for (int i = 0; i < 8; i++) o += pmt[u][i] * wo[j][i];
                float y = xv[u][j] + SCALE_C * o;
                yv[u][j] = y;
                s1[u] += y;
                s2[u] += y * y;
            }
        }

        float v[2];
#pragma unroll
        for (int u = 0; u < 2; u++) {
            float ls = b5 ? s1[u] : s2[u];
            v[u] = (b5 ? s2[u] : s1[u]) + __shfl_xor(ls, 32, 64);
        }
#pragma unroll
        for (int u = 0; u < 2; u++) v[u] += __shfl_xor(v[u], 16, 64);
#pragma unroll
        for (int u = 0; u < 2; u++) v[u] += __shfl_xor(v[u], 8, 64);
#pragma unroll
        for (int u = 0; u < 2; u++) v[u] += __shfl_xor(v[u], 4, 64);
#pragma unroll
        for (int u = 0; u < 2; u++) v[u] += __shfl_xor(v[u], 2, 64);
#pragma unroll
        for (int u = 0; u < 2; u++) v[u] += __shfl_xor(v[u], 1, 64);

#pragma unroll
        for (int u = 0; u < 2; u++) {
            float vw = __shfl_xor(v[u], 32, 64);
            float S1 = b5 ? vw : v[u];
            float S2 = b5 ? v[u] : vw;
            float mu = S1 * (1.0f / DIMD);
            float var = S2 * (1.0f / DIMD) - mu * mu;
            float rs = rsqrtf(var + EPS_C);

            float* po = out + (rowbase + r + u) * DIMD + d0;
            f32x4 o1 = { g[0] * (yv[u][0] - mu) * rs + be[0],
                         g[1] * (yv[u][1] - mu) * rs + be[1],
                         g[2] * (yv[u][2] - mu) * rs + be[2],
                         g[3] * (yv[u][3] - mu) * rs + be[3] };
            f32x4 o2 = { g[4] * (yv[u][4] - mu) * rs + be[4],
                         g[5] * (yv[u][5] - mu) * rs + be[5],
                         g[6] * (yv[u][6] - mu) * rs + be[6],
                         g[7] * (yv[u][7] - mu) * rs + be[7] };
            __builtin_nontemporal_store(o1, (f32x4*)po);
            __builtin_nontemporal_store(o2, (f32x4*)(po + 4));
        }

#pragma unroll
        for (int u = 0; u < 2; u++)
#pragma unroll
            for (int j = 0; j < 8; j++) xv[u][j] = xn[u][j];
    }
}

// ---------------------------------------------------------------------------
// Pass 2: fold mean-field through Cayley into per-batch WoT[d][i], c2[d].
__global__ __launch_bounds__(64) void kfold(const float* __restrict__ wsum,
                                            const float* __restrict__ Wm,
                                            const float* __restrict__ bm,
                                            const float* __restrict__ Wo,
                                            const float* __restrict__ bo,
                                            const float* __restrict__ bp,
                                            float* __restrict__ wot,
                                            float* __restrict__ c2) {
    const int b = blockIdx.x;
    const int l = threadIdx.x;
    const float invN = 1.0f / (float)NN;

    float m[8];
#pragma unroll
    for (int j = 0; j < 8; j++) m[j] = wsum[b * DIMD + l * 8 + j] * invN;

    float mf[8];
#pragma unroll
    for (int i = 0; i < 8; i++) {
        float wmr[8];
        load8f(Wm + i * DIMD + l * 8, wmr);
        float p = 0.0f;
#pragma unroll
        for (int j = 0; j < 8; j++) p += m[j] * wmr[j];
#pragma unroll
        for (int off = 32; off >= 1; off >>= 1) p += __shfl_xor(p, off, 64);
        mf[i] = p + bm[i];
    }

    const int masks[8] = {0, 1, 2, 4, 3, 5, 6, 7};
    const int invm[8]  = {0, 1, 2, 4, 3, 5, 6, 7};
    float T[8][8];
#pragma unroll
    for (int i = 0; i < 8; i++) {
#pragma unroll
        for (int k = 0; k < 8; k++) {
            int bmask = masks[i] ^ masks[k];
            int j = invm[bmask];
            int s = 0, aa = masks[i] >> 1;
            while (aa) { s += __popc(aa & bmask); aa >>= 1; }
            T[i][k] = (s & 1) ? -mf[j] : mf[j];
        }
    }

    float cv[8];
#pragma unroll
    for (int k = 0; k < 8; k++) {
        float s = 0.0f;
#pragma unroll
        for (int i = 0; i < 8; i++) s += bp[i] * T[i][k];
        cv[k] = s;
    }

#pragma unroll
    for (int j = 0; j < 8; j++) {
        int d = l * 8 + j;
        float wor[8];
        load8f(Wo + d * 8, wor);
        float cc = bo[d];
#pragma unroll
        for (int k = 0; k < 8; k++) cc += cv[k] * wor[k];
        c2[b * DIMD + d] = cc;
#pragma unroll
        for (int i = 0; i < 8; i++) {
            float s = 0.0f;
#pragma unroll
            for (int k = 0; k < 8; k++) s += T[i][k] * wor[k];
            wot[((long)b * DIMD + d) * 8 + i] = s;
        }
    }
}

extern "C" void kernel_launch(void* const* d_in, const int* in_sizes, int n_in,
                              void* d_out, int out_size, void* d_ws, size_t ws_size,
                              hipStream_t stream) {
    const float* x     = (const float*)d_in[0];
    const float* Wp    = (const float*)d_in[1];
    const float* bp    = (const float*)d_in[2];
    const float* Wm    = (const float*)d_in[3];
    const float* bm    = (const float*)d_in[4];
    const float* Wo    = (const float*)d_in[5];
    const float* bo    = (const float*)d_in[6];
    const float* gamma = (const float*)d_in[7];
    const float* beta  = (const float*)d_in[8];

    float* ws   = (float*)d_ws;
    float* wsum = ws;                 // 4096 floats
    float* wot  = ws + 4096;          // 32768 floats
    float* c2   = ws + 4096 + 32768;  // 4096 floats
    float* pmws = ws + 40960;         // BB*NN*8 = 1048576 floats (4 MiB)

    const size_t need = (size_t)(40960 + (long)BB * NN * 8) * sizeof(float);

    kzero<<<16, 256, 0, stream>>>(wsum, BB * DIMD);
    if (ws_size >= need) {
        kmean2<<<dim3(128, 8), 256, 0, stream>>>(x, Wp, wsum, pmws);
        kfold<<<8, 64, 0, stream>>>(wsum, Wm, bm, Wo, bo, bp, wot, c2);
        kmain2<<<dim3(128, 8), 256, 0, stream>>>(x, gamma, beta, wot, c2, pmws, (float*)d_out);
    } else {
        kmean<<<dim3(128, 8), 256, 0, stream>>>(x, wsum);
        kfold<<<8, 64, 0, stream>>>(wsum, Wm, bm, Wo, bo, bp, wot, c2);
        kmain<<<dim3(128, 8), 256, 0, stream>>>(x, Wp, gamma, beta, wot, c2, (float*)d_out);
    }
}